// Round 1
// 754.907 us; speedup vs baseline: 1.0855x; 1.0855x over previous
//
#include <hip/hip_runtime.h>
#include <hip/hip_bf16.h>
#include <stdint.h>

#define Bb 32
#define Tt 2048
#define Hh 1024

typedef __bf16 bf16;
typedef __bf16 bf16x8 __attribute__((ext_vector_type(8)));
typedef __bf16 bf16x4 __attribute__((ext_vector_type(4)));
typedef float  f32x4  __attribute__((ext_vector_type(4)));

__device__ __forceinline__ float tanh_fast(float x){
    // tanh(x) = 1 - 2/(exp(2x)+1); safe at +-inf (exp->inf gives 1, exp->0 gives -1)
    float e = __expf(2.0f*x);
    return 1.0f - 2.0f/(e + 1.0f);
}

__device__ __forceinline__ void gl2lds16(const void* g, void* l){
    __builtin_amdgcn_global_load_lds(
        (const __attribute__((address_space(1))) uint32_t*)g,
        (__attribute__((address_space(3))) uint32_t*)l, 16, 0, 0);
}

// ---- K1: copy prev_s -> out (f32 exact) + optional bf16 convert into ws ----
// outp region is write-only for the rest of the launch -> nontemporal stores
// (keeps L2/L3 capacity for the gemm's A-stream).
__global__ __launch_bounds__(256) void k_copy_conv(
    const float* __restrict__ prev, float* __restrict__ outp, bf16* __restrict__ abf)
{
    long i = (long)blockIdx.x*256 + threadIdx.x;     // float4 index, < 16777216
    f32x4 v = __builtin_nontemporal_load(&((const f32x4*)prev)[i]);
    long b = i >> 19;                                // / (T*H/4) = 2^19
    __builtin_nontemporal_store(v, &((f32x4*)outp)[i + (b<<8)]);
    if (abf){
        bf16x4 h = { (bf16)v.x,(bf16)v.y,(bf16)v.z,(bf16)v.w };
        ((bf16x4*)abf)[i] = h;                       // cached: gemm + ct re-read this
    }
}

// ---- K1b: W_prev f32 -> bf16 ----
__global__ __launch_bounds__(256) void k_wconv(const float* __restrict__ w, bf16* __restrict__ wb)
{
    long i = (long)blockIdx.x*256 + threadIdx.x;     // < 262144
    f32x4 v = ((const f32x4*)w)[i];
    bf16x4 h = { (bf16)v.x,(bf16)v.y,(bf16)v.z,(bf16)v.w };
    ((bf16x4*)wb)[i] = h;
}

// ---- K1c: s_t row -> prev_s_new[:, T, :] ----
__global__ __launch_bounds__(256) void k_strow(const float* __restrict__ s_t, float* __restrict__ outp)
{
    int b = blockIdx.x;
    f32x4 v = ((const f32x4*)(s_t + (size_t)b*Hh))[threadIdx.x];
    ((f32x4*)(outp + (size_t)b*(Tt+1)*Hh + (size_t)Tt*Hh))[threadIdx.x] = v;
}

// ---- K2: dec_fea[b,d] = sum_h s_t[b,h]*W_s[d,h] + b_s[d] ; wave per output ----
__global__ __launch_bounds__(256) void k_decfea(
    const float* __restrict__ s_t, const float* __restrict__ Ws,
    const float* __restrict__ bs, float* __restrict__ dec)
{
    int o = blockIdx.x*4 + (threadIdx.x>>6);         // grid 8192 -> o < 32768
    int lane = threadIdx.x & 63;
    int b = o >> 10, d = o & 1023;
    const f32x4* sr = (const f32x4*)(s_t + (size_t)b*Hh);
    const f32x4* wr = (const f32x4*)(Ws  + (size_t)d*Hh);
    float sum = 0.f;
    #pragma unroll
    for (int it=0; it<4; ++it){
        f32x4 a = sr[it*64+lane], w = wr[it*64+lane];
        sum += a.x*w.x + a.y*w.y + a.z*w.z + a.w*w.w;
    }
    #pragma unroll
    for (int off=32; off>=1; off>>=1) sum += __shfl_xor(sum, off, 64);
    if (lane==0) dec[o] = sum + bs[d];
}

// ---- K3: fused GEMM (prev_s @ W_prev^T) + tanh + v-dot -> scores[b,t] ----
// 128x128 tile, BK=64, 256 thr = 2x2 waves of 64x64 (4x4 frags of 16x16x32).
// Double-buffered pipelined K-loop ("2-phase"): issue next tile's
// global_load_lds BEFORE computing current tile, one __syncthreads per iter
// (its vmcnt(0)+lgkmcnt(0) drain is the only wait). Load latency hides under
// the 32 MFMAs + ds_reads of the current tile.
// Block decode: the 8 col-tiles of one row-strip sit at flat indices f,f+8,
// ...,f+56 -> same XCD (round-robin i%8) and temporally adjacent -> each A
// k-slab is fetched from HBM once and L2-hit by the other 7 col-blocks.
template<bool WS>
__global__ __launch_bounds__(256) void k_gemm_score(
    const bf16* __restrict__ Ab, const float* __restrict__ Af,
    const bf16* __restrict__ Wb, const float* __restrict__ Wf,
    const float* __restrict__ dec, const float* __restrict__ v,
    float* __restrict__ scores)
{
    __shared__ __align__(16) bf16 lA[2][128*64];
    __shared__ __align__(16) bf16 lB[2][128*64];
    __shared__ float rowsum[128];
    const int tid  = threadIdx.x;
    const int wave = tid>>6, lane = tid&63, quad = lane>>4, l15 = lane&15;
    const int wm = wave>>1, wn = wave&1;
    const int f = blockIdx.x;                        // 4096 blocks
    const int row0 = (((f>>6)<<3) + (f&7)) * 128;    // over B*T (512 strips)
    const int col0 = ((f>>3)&7) * 128;               // over d (8 tiles)
    if (tid < 128) rowsum[tid] = 0.f;

    int Lm[4], Loct[4];
    #pragma unroll
    for (int it=0; it<4; ++it){ int L=it*256+tid; Lm[it]=L&127; Loct[it]=L>>7; }

    f32x4 acc[4][4] = {};

    // LDS layout [k-oct][row] in 16B units: matches global_load_lds
    // wave-uniform contiguous destination AND gives 2-way (free) ds_read_b128
    // bank aliasing.
    auto stageW = [&](bf16* dA, bf16* dB, int kc){
        const int k0 = kc*64;
        #pragma unroll
        for (int it=0; it<4; ++it){
            int L = it*256+tid;
            gl2lds16(Ab + (size_t)(row0+Lm[it])*Hh + k0 + Loct[it]*8, dA + (size_t)L*8);
        }
        #pragma unroll
        for (int it=0; it<4; ++it){
            int L = it*256+tid;
            gl2lds16(Wb + (size_t)(col0+Lm[it])*Hh + k0 + Loct[it]*8, dB + (size_t)L*8);
        }
    };
    auto stageF = [&](bf16* dA, bf16* dB, int kc){
        const int k0 = kc*64;
        #pragma unroll
        for (int it=0; it<4; ++it){
            int L = it*256+tid;
            const f32x4* g = (const f32x4*)(Af + (size_t)(row0+Lm[it])*Hh + k0 + Loct[it]*8);
            f32x4 x0=g[0], x1=g[1];
            bf16x8 r = {(bf16)x0.x,(bf16)x0.y,(bf16)x0.z,(bf16)x0.w,
                        (bf16)x1.x,(bf16)x1.y,(bf16)x1.z,(bf16)x1.w};
            *(bf16x8*)(dA + (size_t)L*8) = r;
        }
        #pragma unroll
        for (int it=0; it<4; ++it){
            int L = it*256+tid;
            const f32x4* g = (const f32x4*)(Wf + (size_t)(col0+Lm[it])*Hh + k0 + Loct[it]*8);
            f32x4 x0=g[0], x1=g[1];
            bf16x8 r = {(bf16)x0.x,(bf16)x0.y,(bf16)x0.z,(bf16)x0.w,
                        (bf16)x1.x,(bf16)x1.y,(bf16)x1.z,(bf16)x1.w};
            *(bf16x8*)(dB + (size_t)L*8) = r;
        }
    };

    bf16 *cA = lA[0], *cB = lB[0], *nA = lA[1], *nB = lB[1];
    if (WS) stageW(cA, cB, 0); else stageF(cA, cB, 0);
    __syncthreads();

    for (int kc=0; kc<16; ++kc){
        if (kc < 15){ if (WS) stageW(nA, nB, kc+1); else stageF(nA, nB, kc+1); }
        #pragma unroll
        for (int ks=0; ks<2; ++ks){
            bf16x8 afr[4], bfr[4];
            const int ob = (ks*4+quad)*128;          // oct*rows
            #pragma unroll
            for (int tr=0; tr<4; ++tr)
                afr[tr] = *(const bf16x8*)(cA + (size_t)(ob + wm*64 + tr*16 + l15)*8);
            #pragma unroll
            for (int tc=0; tc<4; ++tc)
                bfr[tc] = *(const bf16x8*)(cB + (size_t)(ob + wn*64 + tc*16 + l15)*8);
            #pragma unroll
            for (int tr=0; tr<4; ++tr)
                #pragma unroll
                for (int tc=0; tc<4; ++tc)
                    acc[tr][tc] = __builtin_amdgcn_mfma_f32_16x16x32_bf16(
                        afr[tr], bfr[tc], acc[tr][tc], 0, 0, 0);
        }
        __syncthreads();                             // drains vmcnt+lgkm: next buf
        bf16* t;                                     // staged, cur reads done
        t = cA; cA = nA; nA = t;
        t = cB; cB = nB; nB = t;
    }

    // epilogue: scores partial = sum_d v[d]*tanh(c + dec[b,d])
    const int b = row0 >> 11;                        // T = 2048 rows per batch
    float df[4], vv[4];
    #pragma unroll
    for (int tc=0; tc<4; ++tc){
        int d = col0 + wn*64 + tc*16 + l15;          // C/D col = lane&15
        df[tc] = dec[b*Hh + d];
        vv[tc] = v[d];
    }
    #pragma unroll
    for (int tr=0; tr<4; ++tr){
        #pragma unroll
        for (int i=0; i<4; ++i){                     // C/D row = quad*4 + reg
            float p = 0.f;
            #pragma unroll
            for (int tc=0; tc<4; ++tc)
                p += vv[tc]*tanh_fast(acc[tr][tc][i] + df[tc]);
            p += __shfl_xor(p,1,64); p += __shfl_xor(p,2,64);
            p += __shfl_xor(p,4,64); p += __shfl_xor(p,8,64);
            if (l15==0) atomicAdd(&rowsum[wm*64 + tr*16 + quad*4 + i], p);
        }
    }
    __syncthreads();
    if (tid < 128)
        atomicAdd(&scores[(size_t)b*Tt + (row0 & (Tt-1)) + tid], rowsum[tid]);
}

// ---- K4: softmax over t (2048) per batch ----
__global__ __launch_bounds__(256) void k_softmax(const float* __restrict__ sc, float* __restrict__ at)
{
    __shared__ float red[4];
    const int b = blockIdx.x, tid = threadIdx.x;
    const int wave = tid>>6, lane = tid&63;
    float s[8]; float mx = -3.4e38f;
    #pragma unroll
    for (int i=0;i<8;++i){ s[i] = sc[(size_t)b*Tt + tid + i*256]; mx = fmaxf(mx, s[i]); }
    #pragma unroll
    for (int off=32; off>=1; off>>=1) mx = fmaxf(mx, __shfl_xor(mx, off, 64));
    if (lane==0) red[wave]=mx;
    __syncthreads();
    mx = fmaxf(fmaxf(red[0],red[1]), fmaxf(red[2],red[3]));
    float sum=0.f;
    #pragma unroll
    for (int i=0;i<8;++i){ s[i]=__expf(s[i]-mx); sum+=s[i]; }
    #pragma unroll
    for (int off=32; off>=1; off>>=1) sum += __shfl_xor(sum, off, 64);
    __syncthreads();
    if (lane==0) red[wave]=sum;
    __syncthreads();
    sum = red[0]+red[1]+red[2]+red[3];
    float inv = 1.0f/sum;
    #pragma unroll
    for (int i=0;i<8;++i) at[(size_t)b*Tt + tid + i*256] = s[i]*inv;
}

// ---- K5: ct[b,h] = sum_t at[b,t]*prev_s[b,t,h]; t split across 16 blocks ----
// PART=true: plain partial stores to ctp[tcn][b][h] (no cross-XCD atomic
// ping-pong), reduced by k_ctred. PART=false: legacy atomic fallback.
template<bool WS, bool PART>
__global__ __launch_bounds__(256) void k_ct(
    const bf16* __restrict__ Ab, const float* __restrict__ Af,
    const float* __restrict__ at, float* __restrict__ out)
{
    const int b = blockIdx.x, tcn = blockIdx.y, tid = threadIdx.x;
    float a0=0,a1=0,a2=0,a3=0;
    const int tBase = tcn*128;
    #pragma unroll 4
    for (int tt=0; tt<128; ++tt){
        int t = tBase+tt;
        float w = at[(size_t)b*Tt + t];
        if (WS){
            bf16x4 x = ((const bf16x4*)(Ab + ((size_t)b*Tt + t)*Hh))[tid];
            a0 += w*(float)x[0]; a1 += w*(float)x[1];
            a2 += w*(float)x[2]; a3 += w*(float)x[3];
        } else {
            f32x4 x = ((const f32x4*)(Af + ((size_t)b*Tt + t)*Hh))[tid];
            a0 += w*x.x; a1 += w*x.y; a2 += w*x.z; a3 += w*x.w;
        }
    }
    if (PART){
        f32x4 r = {a0,a1,a2,a3};
        ((f32x4*)(out + ((size_t)tcn*Bb + b)*Hh))[tid] = r;
    } else {
        float* o = out + (size_t)b*Hh + tid*4;
        atomicAdd(o+0,a0); atomicAdd(o+1,a1); atomicAdd(o+2,a2); atomicAdd(o+3,a3);
    }
}

// ---- K5b: reduce 16 ct partials ----
__global__ __launch_bounds__(256) void k_ctred(const float* __restrict__ part, float* __restrict__ ct)
{
    const int b = blockIdx.x, tid = threadIdx.x;
    f32x4 s = {0.f,0.f,0.f,0.f};
    #pragma unroll
    for (int p=0;p<16;++p){
        f32x4 x = ((const f32x4*)(part + ((size_t)p*Bb + b)*Hh))[tid];
        s.x+=x.x; s.y+=x.y; s.z+=x.z; s.w+=x.w;
    }
    ((f32x4*)(ct + (size_t)b*Hh))[tid] = s;
}

extern "C" void kernel_launch(void* const* d_in, const int* in_sizes, int n_in,
                              void* d_out, int out_size, void* d_ws, size_t ws_size,
                              hipStream_t stream)
{
    const float* s_t  = (const float*)d_in[0];
    const float* prev = (const float*)d_in[1];
    const float* Wp   = (const float*)d_in[2];
    const float* Ws   = (const float*)d_in[3];
    const float* bs   = (const float*)d_in[4];
    const float* v    = (const float*)d_in[5];
    float* ct   = (float*)d_out;
    float* outp = ct + (size_t)Bb*Hh;                // prev_s_new region

    char* ws = (char*)d_ws;
    const size_t ABF = (size_t)Bb*Tt*Hh*2;           // 128 MB bf16 A
    const size_t WBF = (size_t)Hh*Hh*2;              // 2 MB bf16 W_prev
    const size_t SMALL = (size_t)(32768 + Bb*Tt + Bb*Tt)*4;
    const size_t CTP = (size_t)16*Bb*Hh*4;           // 2 MB ct partials
    bool big   = ws_size >= ABF + WBF + SMALL;
    bool bigct = ws_size >= ABF + WBF + SMALL + CTP;

    bf16 *abf=nullptr, *wbf=nullptr;
    float *dec, *scores, *at, *ctp=nullptr;
    if (big){
        abf = (bf16*)ws; wbf = (bf16*)(ws + ABF);
        dec = (float*)(ws + ABF + WBF);
    } else {
        dec = (float*)ws;
    }
    scores = dec + 32768;
    at     = scores + (size_t)Bb*Tt;
    if (bigct) ctp = at + (size_t)Bb*Tt;

    hipMemsetAsync(d_out, 0, (size_t)Bb*Hh*4, stream);               // ct accum
    hipMemsetAsync((void*)scores, 0, (size_t)Bb*Tt*4, stream);       // score accum

    k_copy_conv<<<65536,256,0,stream>>>(prev, outp, abf);
    if (big) k_wconv<<<1024,256,0,stream>>>(Wp, wbf);
    k_strow<<<Bb,256,0,stream>>>(s_t, outp);
    k_decfea<<<8192,256,0,stream>>>(s_t, Ws, bs, dec);
    if (big)
        k_gemm_score<true ><<<4096,256,0,stream>>>(abf, nullptr, wbf, nullptr, dec, v, scores);
    else
        k_gemm_score<false><<<4096,256,0,stream>>>(nullptr, prev, nullptr, Wp, dec, v, scores);
    k_softmax<<<Bb,256,0,stream>>>(scores, at);
    if (big){
        if (bigct){
            k_ct<true,true ><<<dim3(Bb,16),256,0,stream>>>(abf, nullptr, at, ctp);
            k_ctred<<<Bb,256,0,stream>>>(ctp, ct);
        } else {
            k_ct<true,false><<<dim3(Bb,16),256,0,stream>>>(abf, nullptr, at, ct);
        }
    } else {
        k_ct<false,false><<<dim3(Bb,16),256,0,stream>>>(nullptr, prev, at, ct);
    }
}

// Round 2
// 653.266 us; speedup vs baseline: 1.2544x; 1.1556x over previous
//
#include <hip/hip_runtime.h>
#include <hip/hip_bf16.h>
#include <stdint.h>

#define Bb 32
#define Tt 2048
#define Hh 1024

typedef __bf16 bf16;
typedef __bf16 bf16x8 __attribute__((ext_vector_type(8)));
typedef __bf16 bf16x4 __attribute__((ext_vector_type(4)));
typedef float  f32x4  __attribute__((ext_vector_type(4)));

__device__ __forceinline__ float tanh_fast(float x){
    // tanh(x) = 1 - 2/(exp(2x)+1); safe at +-inf (exp->inf gives 1, exp->0 gives -1)
    float e = __expf(2.0f*x);
    return 1.0f - 2.0f/(e + 1.0f);
}

__device__ __forceinline__ void gl2lds16(const void* g, void* l){
    __builtin_amdgcn_global_load_lds(
        (const __attribute__((address_space(1))) uint32_t*)g,
        (__attribute__((address_space(3))) uint32_t*)l, 16, 0, 0);
}

// ---- K1: copy prev_s -> out (f32 exact) + optional bf16 convert into ws ----
// outp region is write-only for the rest of the launch -> nontemporal stores
// (keeps L2/L3 capacity for the gemm's A-stream).
__global__ __launch_bounds__(256) void k_copy_conv(
    const float* __restrict__ prev, float* __restrict__ outp, bf16* __restrict__ abf)
{
    long i = (long)blockIdx.x*256 + threadIdx.x;     // float4 index, < 16777216
    f32x4 v = __builtin_nontemporal_load(&((const f32x4*)prev)[i]);
    long b = i >> 19;                                // / (T*H/4) = 2^19
    __builtin_nontemporal_store(v, &((f32x4*)outp)[i + (b<<8)]);
    if (abf){
        bf16x4 h = { (bf16)v.x,(bf16)v.y,(bf16)v.z,(bf16)v.w };
        ((bf16x4*)abf)[i] = h;                       // cached: gemm + ct re-read this
    }
}

// ---- K1b: W_prev f32 -> bf16 ----
__global__ __launch_bounds__(256) void k_wconv(const float* __restrict__ w, bf16* __restrict__ wb)
{
    long i = (long)blockIdx.x*256 + threadIdx.x;     // < 262144
    f32x4 v = ((const f32x4*)w)[i];
    bf16x4 h = { (bf16)v.x,(bf16)v.y,(bf16)v.z,(bf16)v.w };
    ((bf16x4*)wb)[i] = h;
}

// ---- K1c: s_t row -> prev_s_new[:, T, :] ----
__global__ __launch_bounds__(256) void k_strow(const float* __restrict__ s_t, float* __restrict__ outp)
{
    int b = blockIdx.x;
    f32x4 v = ((const f32x4*)(s_t + (size_t)b*Hh))[threadIdx.x];
    ((f32x4*)(outp + (size_t)b*(Tt+1)*Hh + (size_t)Tt*Hh))[threadIdx.x] = v;
}

// ---- K2: dec_fea[b,d] = sum_h s_t[b,h]*W_s[d,h] + b_s[d] ; wave per output ----
__global__ __launch_bounds__(256) void k_decfea(
    const float* __restrict__ s_t, const float* __restrict__ Ws,
    const float* __restrict__ bs, float* __restrict__ dec)
{
    int o = blockIdx.x*4 + (threadIdx.x>>6);         // grid 8192 -> o < 32768
    int lane = threadIdx.x & 63;
    int b = o >> 10, d = o & 1023;
    const f32x4* sr = (const f32x4*)(s_t + (size_t)b*Hh);
    const f32x4* wr = (const f32x4*)(Ws  + (size_t)d*Hh);
    float sum = 0.f;
    #pragma unroll
    for (int it=0; it<4; ++it){
        f32x4 a = sr[it*64+lane], w = wr[it*64+lane];
        sum += a.x*w.x + a.y*w.y + a.z*w.z + a.w*w.w;
    }
    #pragma unroll
    for (int off=32; off>=1; off>>=1) sum += __shfl_xor(sum, off, 64);
    if (lane==0) dec[o] = sum + bs[d];
}

// ---- K3: fused GEMM (prev_s @ W_prev^T) + tanh + v-dot -> scores partials ----
// 128x128 tile, BK=64, 256 thr = 2x2 waves of 64x64 (4x4 frags of 16x16x32).
// Double-buffered pipelined K-loop: issue next tile's global_load_lds BEFORE
// computing current tile; one __syncthreads per iter.
// LDS: row-major [128 rows][8 chunks of 16B] so each wave's global_load_lds
// covers 8 contiguous 128B row-slabs (16 fully-used cache lines vs the
// oct-major layout's 64 quarter-used lines). Bank conflicts on the fragment
// ds_read_b128 are killed by an XOR involution on the chunk index
// (chunk ^= row&7), applied to BOTH the global SOURCE address (LDS dest stays
// linear, as global_load_lds requires) and the read address (rule: same
// involution both sides or neither).
// Block decode: the 8 col-tiles of one row-strip sit at flat indices f,f+8,
// ...,f+56 -> same XCD (round-robin i%8) and temporally adjacent -> each A
// k-slab is fetched from HBM once and L2-hit by the other 7 col-blocks.
template<bool WS>
__global__ __launch_bounds__(256) void k_gemm_score(
    const bf16* __restrict__ Ab, const float* __restrict__ Af,
    const bf16* __restrict__ Wb, const float* __restrict__ Wf,
    const float* __restrict__ dec, const float* __restrict__ v,
    float* __restrict__ scp)
{
    __shared__ __align__(16) bf16 lA[2][128*64];
    __shared__ __align__(16) bf16 lB[2][128*64];
    __shared__ float rowsum[128];
    const int tid  = threadIdx.x;
    const int wave = tid>>6, lane = tid&63, quad = lane>>4, l15 = lane&15;
    const int wm = wave>>1, wn = wave&1;
    const int f = blockIdx.x;                        // 4096 blocks
    const int row0 = (((f>>6)<<3) + (f&7)) * 128;    // over B*T (512 strips)
    const int ct8 = (f>>3)&7;                        // col-tile index
    const int col0 = ct8 * 128;                      // over d (8 tiles)
    if (tid < 128) rowsum[tid] = 0.f;

    f32x4 acc[4][4] = {};

    auto stageW = [&](bf16* dA, bf16* dB, int kc){
        const int k0 = kc*64;
        #pragma unroll
        for (int it=0; it<4; ++it){
            int L = it*256+tid;
            int r = L>>3;                            // local row 0..127
            int oc = (L&7) ^ (r&7);                  // source chunk (involution)
            gl2lds16(Ab + (size_t)(row0+r)*Hh + k0 + oc*8, dA + (size_t)L*8);
        }
        #pragma unroll
        for (int it=0; it<4; ++it){
            int L = it*256+tid;
            int r = L>>3;
            int oc = (L&7) ^ (r&7);
            gl2lds16(Wb + (size_t)(col0+r)*Hh + k0 + oc*8, dB + (size_t)L*8);
        }
    };
    auto stageF = [&](bf16* dA, bf16* dB, int kc){
        const int k0 = kc*64;
        #pragma unroll
        for (int it=0; it<4; ++it){
            int L = it*256+tid;
            int r = L>>3, oc = L&7;
            const f32x4* g = (const f32x4*)(Af + (size_t)(row0+r)*Hh + k0 + oc*8);
            f32x4 x0=g[0], x1=g[1];
            bf16x8 rr = {(bf16)x0.x,(bf16)x0.y,(bf16)x0.z,(bf16)x0.w,
                         (bf16)x1.x,(bf16)x1.y,(bf16)x1.z,(bf16)x1.w};
            *(bf16x8*)(dA + ((size_t)r*8 + (oc ^ (r&7)))*8) = rr;
        }
        #pragma unroll
        for (int it=0; it<4; ++it){
            int L = it*256+tid;
            int r = L>>3, oc = L&7;
            const f32x4* g = (const f32x4*)(Wf + (size_t)(col0+r)*Hh + k0 + oc*8);
            f32x4 x0=g[0], x1=g[1];
            bf16x8 rr = {(bf16)x0.x,(bf16)x0.y,(bf16)x0.z,(bf16)x0.w,
                         (bf16)x1.x,(bf16)x1.y,(bf16)x1.z,(bf16)x1.w};
            *(bf16x8*)(dB + ((size_t)r*8 + (oc ^ (r&7)))*8) = rr;
        }
    };

    bf16 *cA = lA[0], *cB = lB[0], *nA = lA[1], *nB = lB[1];
    if (WS) stageW(cA, cB, 0); else stageF(cA, cB, 0);
    __syncthreads();

    for (int kc=0; kc<16; ++kc){
        if (kc < 15){ if (WS) stageW(nA, nB, kc+1); else stageF(nA, nB, kc+1); }
        #pragma unroll
        for (int ks=0; ks<2; ++ks){
            bf16x8 afr[4], bfr[4];
            const int ob = ks*4 + quad;              // k-chunk 0..7
            #pragma unroll
            for (int tr=0; tr<4; ++tr){
                int r = wm*64 + tr*16 + l15;
                afr[tr] = *(const bf16x8*)(cA + ((size_t)r*8 + (ob ^ (r&7)))*8);
            }
            #pragma unroll
            for (int tc=0; tc<4; ++tc){
                int r = wn*64 + tc*16 + l15;
                bfr[tc] = *(const bf16x8*)(cB + ((size_t)r*8 + (ob ^ (r&7)))*8);
            }
            #pragma unroll
            for (int tr=0; tr<4; ++tr)
                #pragma unroll
                for (int tc=0; tc<4; ++tc)
                    acc[tr][tc] = __builtin_amdgcn_mfma_f32_16x16x32_bf16(
                        afr[tr], bfr[tc], acc[tr][tc], 0, 0, 0);
        }
        __syncthreads();                             // drains vmcnt+lgkm: next buf
        bf16* t;                                     // staged, cur reads done
        t = cA; cA = nA; nA = t;
        t = cB; cB = nB; nB = t;
    }

    // epilogue: scores partial = sum_d v[d]*tanh(c + dec[b,d])
    const int b = row0 >> 11;                        // T = 2048 rows per batch
    float df[4], vv[4];
    #pragma unroll
    for (int tc=0; tc<4; ++tc){
        int d = col0 + wn*64 + tc*16 + l15;          // C/D col = lane&15
        df[tc] = dec[b*Hh + d];
        vv[tc] = v[d];
    }
    #pragma unroll
    for (int tr=0; tr<4; ++tr){
        #pragma unroll
        for (int i=0; i<4; ++i){                     // C/D row = quad*4 + reg
            float p = 0.f;
            #pragma unroll
            for (int tc=0; tc<4; ++tc)
                p += vv[tc]*tanh_fast(acc[tr][tc][i] + df[tc]);
            p += __shfl_xor(p,1,64); p += __shfl_xor(p,2,64);
            p += __shfl_xor(p,4,64); p += __shfl_xor(p,8,64);
            if (l15==0) atomicAdd(&rowsum[wm*64 + tr*16 + quad*4 + i], p);
        }
    }
    __syncthreads();
    if (tid < 128)                                   // plain store: per-col-tile slab
        scp[(size_t)ct8*Bb*Tt + (size_t)b*Tt + (row0 & (Tt-1)) + tid] = rowsum[tid];
}

// ---- K4: softmax over t (2048) per batch; reduces the 8 col-tile partials ----
__global__ __launch_bounds__(256) void k_softmax(const float* __restrict__ scp, float* __restrict__ at)
{
    __shared__ float red[4];
    const int b = blockIdx.x, tid = threadIdx.x;
    const int wave = tid>>6, lane = tid&63;
    float s[8]; float mx = -3.4e38f;
    #pragma unroll
    for (int i=0;i<8;++i){
        size_t idx = (size_t)b*Tt + tid + i*256;
        float acc = 0.f;
        #pragma unroll
        for (int p=0;p<8;++p) acc += scp[(size_t)p*Bb*Tt + idx];
        s[i] = acc; mx = fmaxf(mx, acc);
    }
    #pragma unroll
    for (int off=32; off>=1; off>>=1) mx = fmaxf(mx, __shfl_xor(mx, off, 64));
    if (lane==0) red[wave]=mx;
    __syncthreads();
    mx = fmaxf(fmaxf(red[0],red[1]), fmaxf(red[2],red[3]));
    float sum=0.f;
    #pragma unroll
    for (int i=0;i<8;++i){ s[i]=__expf(s[i]-mx); sum+=s[i]; }
    #pragma unroll
    for (int off=32; off>=1; off>>=1) sum += __shfl_xor(sum, off, 64);
    __syncthreads();
    if (lane==0) red[wave]=sum;
    __syncthreads();
    sum = red[0]+red[1]+red[2]+red[3];
    float inv = 1.0f/sum;
    #pragma unroll
    for (int i=0;i<8;++i) at[(size_t)b*Tt + tid + i*256] = s[i]*inv;
}

// ---- K5: ct[b,h] = sum_t at[b,t]*prev_s[b,t,h]; t split across 16 blocks ----
// PART=true: plain partial stores to ctp[tcn][b][h] (no cross-XCD atomic
// ping-pong), reduced by k_ctred. PART=false: legacy atomic fallback.
template<bool WS, bool PART>
__global__ __launch_bounds__(256) void k_ct(
    const bf16* __restrict__ Ab, const float* __restrict__ Af,
    const float* __restrict__ at, float* __restrict__ out)
{
    const int b = blockIdx.x, tcn = blockIdx.y, tid = threadIdx.x;
    float a0=0,a1=0,a2=0,a3=0;
    const int tBase = tcn*128;
    #pragma unroll 4
    for (int tt=0; tt<128; ++tt){
        int t = tBase+tt;
        float w = at[(size_t)b*Tt + t];
        if (WS){
            bf16x4 x = ((const bf16x4*)(Ab + ((size_t)b*Tt + t)*Hh))[tid];
            a0 += w*(float)x[0]; a1 += w*(float)x[1];
            a2 += w*(float)x[2]; a3 += w*(float)x[3];
        } else {
            f32x4 x = ((const f32x4*)(Af + ((size_t)b*Tt + t)*Hh))[tid];
            a0 += w*x.x; a1 += w*x.y; a2 += w*x.z; a3 += w*x.w;
        }
    }
    if (PART){
        f32x4 r = {a0,a1,a2,a3};
        ((f32x4*)(out + ((size_t)tcn*Bb + b)*Hh))[tid] = r;
    } else {
        float* o = out + (size_t)b*Hh + tid*4;
        atomicAdd(o+0,a0); atomicAdd(o+1,a1); atomicAdd(o+2,a2); atomicAdd(o+3,a3);
    }
}

// ---- K5b: reduce 16 ct partials ----
__global__ __launch_bounds__(256) void k_ctred(const float* __restrict__ part, float* __restrict__ ct)
{
    const int b = blockIdx.x, tid = threadIdx.x;
    f32x4 s = {0.f,0.f,0.f,0.f};
    #pragma unroll
    for (int p=0;p<16;++p){
        f32x4 x = ((const f32x4*)(part + ((size_t)p*Bb + b)*Hh))[tid];
        s.x+=x.x; s.y+=x.y; s.z+=x.z; s.w+=x.w;
    }
    ((f32x4*)(ct + (size_t)b*Hh))[tid] = s;
}

extern "C" void kernel_launch(void* const* d_in, const int* in_sizes, int n_in,
                              void* d_out, int out_size, void* d_ws, size_t ws_size,
                              hipStream_t stream)
{
    const float* s_t  = (const float*)d_in[0];
    const float* prev = (const float*)d_in[1];
    const float* Wp   = (const float*)d_in[2];
    const float* Ws   = (const float*)d_in[3];
    const float* bs   = (const float*)d_in[4];
    const float* v    = (const float*)d_in[5];
    float* ct   = (float*)d_out;
    float* outp = ct + (size_t)Bb*Hh;                // prev_s_new region

    char* ws = (char*)d_ws;
    const size_t ABF = (size_t)Bb*Tt*Hh*2;           // 128 MB bf16 A
    const size_t WBF = (size_t)Hh*Hh*2;              // 2 MB bf16 W_prev
    const size_t SMALL = (size_t)(32768 + 8*Bb*Tt + Bb*Tt)*4;
    const size_t CTP = (size_t)16*Bb*Hh*4;           // 2 MB ct partials
    bool big   = ws_size >= ABF + WBF + SMALL;
    bool bigct = ws_size >= ABF + WBF + SMALL + CTP;

    bf16 *abf=nullptr, *wbf=nullptr;
    float *dec, *scp, *at, *ctp=nullptr;
    if (big){
        abf = (bf16*)ws; wbf = (bf16*)(ws + ABF);
        dec = (float*)(ws + ABF + WBF);
    } else {
        dec = (float*)ws;
    }
    scp = dec + 32768;
    at  = scp + (size_t)8*Bb*Tt;
    if (bigct) ctp = at + (size_t)Bb*Tt;

    hipMemsetAsync(d_out, 0, (size_t)Bb*Hh*4, stream);               // ct accum (atomic fallback)

    k_copy_conv<<<65536,256,0,stream>>>(prev, outp, abf);
    if (big) k_wconv<<<1024,256,0,stream>>>(Wp, wbf);
    k_strow<<<Bb,256,0,stream>>>(s_t, outp);
    k_decfea<<<8192,256,0,stream>>>(s_t, Ws, bs, dec);
    if (big)
        k_gemm_score<true ><<<4096,256,0,stream>>>(abf, nullptr, wbf, nullptr, dec, v, scp);
    else
        k_gemm_score<false><<<4096,256,0,stream>>>(nullptr, prev, nullptr, Wp, dec, v, scp);
    k_softmax<<<Bb,256,0,stream>>>(scp, at);
    if (big){
        if (bigct){
            k_ct<true,true ><<<dim3(Bb,16),256,0,stream>>>(abf, nullptr, at, ctp);
            k_ctred<<<Bb,256,0,stream>>>(ctp, ct);
        } else {
            k_ct<true,false><<<dim3(Bb,16),256,0,stream>>>(abf, nullptr, at, ct);
        }
    } else {
        k_ct<false,false><<<dim3(Bb,16),256,0,stream>>>(nullptr, prev, at, ct);
    }
}